// Round 11
// baseline (6198.462 us; speedup 1.0000x reference)
//
#include <hip/hip_runtime.h>
#include <hip/hip_cooperative_groups.h>
#include <cstdint>

namespace cg = cooperative_groups;

// B=256, H=512, T=192 timesteps, 4H=2048 gate rows.
// Grid: 256 blocks x 256 threads, 1 block/CU (128KB dynamic LDS).
//   blocks [0,128):   layer-0. group g = bid>>6 (batch 128g..), slice s = bid&63
//   blocks [128,256): layer-1. same (g,s) decomposition.
// Slice s owns gate rows n = s*8 + (j&7) + 512*(j>>3), j=0..31.
// Phases p=0..193: L0 computes t=p, L1 computes t=p-1, projection emits t=p-2.
// Precision: h and recurrent W kept as bf16 hi+lo pairs; 4 cross-product MFMAs.
// Sync: stamp barrier (R10, passing 6185us). THIS ROUND'S ONLY CHANGE:
// __launch_bounds__(256, 1) on lstm_kernel -> full VGPR budget (1 wave/SIMD is
// the occupancy anyway, LDS-capped), letting the scheduler hoist many more of
// the unrolled K-loop's sc1 loads ahead of MFMA use (ILP for L3 latency).
// d_ws: [0,16K) stamps (256 x 16 u32); rings hs{0,1}{hi,lo} [4][256][512] bf16.

typedef __bf16 bf16x8 __attribute__((ext_vector_type(8)));
typedef float f32x4 __attribute__((ext_vector_type(4)));

#define SLOT 131072  // 256*512 elements per ring slot

__device__ __forceinline__ uint16_t f2bf(float f) {
    uint32_t u = __builtin_bit_cast(uint32_t, f);
    u += 0x7FFFu + ((u >> 16) & 1u);          // round-to-nearest-even
    return (uint16_t)(u >> 16);
}
__device__ __forceinline__ float bf2f(uint16_t h) {
    return __builtin_bit_cast(float, (uint32_t)h << 16);
}
__device__ __forceinline__ float sigm(float x) { return 1.0f / (1.0f + expf(-x)); }

// agent-scope (cross-XCD coherent, sc1) 16-byte h-fragment load as 2 x u64
__device__ __forceinline__ bf16x8 ld_h16(const uint16_t* p) {
    const uint64_t* q = (const uint64_t*)p;
    uint64_t w0 = __hip_atomic_load(q,     __ATOMIC_RELAXED, __HIP_MEMORY_SCOPE_AGENT);
    uint64_t w1 = __hip_atomic_load(q + 1, __ATOMIC_RELAXED, __HIP_MEMORY_SCOPE_AGENT);
    union { uint64_t u[2]; bf16x8 v; } x;
    x.u[0] = w0; x.u[1] = w1;
    return x.v;
}
__device__ __forceinline__ uint64_t ld_h64(const uint64_t* q) {
    return __hip_atomic_load(q, __ATOMIC_RELAXED, __HIP_MEMORY_SCOPE_AGENT);
}

__global__ void __launch_bounds__(256, 1)
lstm_kernel(const float* __restrict__ x_enc, const float* __restrict__ y_enc,
            const float* __restrict__ Wih0, const float* __restrict__ Whh0,
            const float* __restrict__ bih0, const float* __restrict__ bhh0,
            const float* __restrict__ Wih1, const float* __restrict__ Whh1,
            const float* __restrict__ bih1, const float* __restrict__ bhh1,
            const float* __restrict__ Wout, const float* __restrict__ bout,
            float* __restrict__ out,
            uint32_t* __restrict__ stamp,
            uint16_t* __restrict__ hs0hi, uint16_t* __restrict__ hs0lo,
            uint16_t* __restrict__ hs1hi, uint16_t* __restrict__ hs1lo)
{
    extern __shared__ __align__(16) uint8_t LDS[];
    float* ldsF = (float*)LDS;

    const int tid = threadIdx.x;
    const int bid = blockIdx.x;
    const bool isL0 = (bid < 128);
    const int rb = isL0 ? bid : (bid - 128);
    const int g = rb >> 6;
    const int s = rb & 63;

    const int w  = tid >> 6;   // wave 0..3 -> batch rows w*32..w*32+31 of group
    const int l  = tid & 63;
    const int c  = l & 15;
    const int kg = l >> 4;
    const int h  = c & 7;      // h-index within slice handled by this lane
    const bool lowc = (c < 8);

    // ---------------- one-time init ----------------
    if (isL0) {
        for (int idx = tid; idx < 32 * 512; idx += 256) {
            int j = idx >> 9, k = idx & 511;
            int n = s * 8 + (j & 7) + 512 * (j >> 3);
            float v = Whh0[n * 512 + k];
            uint16_t hi = f2bf(v);
            uint16_t lo = f2bf(v - bf2f(hi));
            uint32_t byte = (uint32_t)(j * 1024 + k * 2) ^ (uint32_t)((j & 7) << 4);
            *(uint16_t*)(LDS + byte) = hi;
            *(uint16_t*)(LDS + 32768 + byte) = lo;
        }
        {   // Wih0 slice (32 rows x 8) fp32
            int j = tid >> 3, k = tid & 7;
            int n = s * 8 + (j & 7) + 512 * (j >> 3);
            ldsF[17408 + tid] = Wih0[n * 8 + k];
        }
    } else {
        for (int idx = tid; idx < 32 * 1024; idx += 256) {
            int j = idx >> 10, k = idx & 1023;
            int n = s * 8 + (j & 7) + 512 * (j >> 3);
            float v = (k < 512) ? Wih1[n * 512 + k] : Whh1[n * 512 + (k - 512)];
            uint16_t hi = f2bf(v);
            uint16_t lo = f2bf(v - bf2f(hi));
            uint32_t byte = (uint32_t)(j * 2048 + k * 2) ^ (uint32_t)((j & 7) << 4);
            *(uint16_t*)(LDS + byte) = hi;
            *(uint16_t*)(LDS + 65536 + byte) = lo;
        }
    }
    float bias[4];
#pragma unroll
    for (int gt = 0; gt < 4; ++gt) {
        int n = s * 8 + h + 512 * gt;
        bias[gt] = isL0 ? (bih0[n] + bhh0[n]) : (bih1[n] + bhh1[n]);
    }
    {   // zero ring slot 3 (t=-1 state) with agent stores (visible past L2)
        int idx = bid * 256 + tid;
        __hip_atomic_store(((uint32_t*)(hs0hi + 3 * SLOT)) + idx, 0u, __ATOMIC_RELAXED, __HIP_MEMORY_SCOPE_AGENT);
        __hip_atomic_store(((uint32_t*)(hs0lo + 3 * SLOT)) + idx, 0u, __ATOMIC_RELAXED, __HIP_MEMORY_SCOPE_AGENT);
        __hip_atomic_store(((uint32_t*)(hs1hi + 3 * SLOT)) + idx, 0u, __ATOMIC_RELAXED, __HIP_MEMORY_SCOPE_AGENT);
        __hip_atomic_store(((uint32_t*)(hs1lo + 3 * SLOT)) + idx, 0u, __ATOMIC_RELAXED, __HIP_MEMORY_SCOPE_AGENT);
    }
    if (tid == 0)   // re-zero own stamp (d_ws is poisoned before every launch)
        __hip_atomic_store(&stamp[bid * 16], 0u, __ATOMIC_RELAXED, __HIP_MEMORY_SCOPE_AGENT);
    float creg[4] = {0.f, 0.f, 0.f, 0.f};   // fp32 cell state (4 batch rows / lane)

    cg::grid_group grid = cg::this_grid();
    grid.sync();   // one-time rendezvous: rings/stamps initialized everywhere

    const int j0 = c, j1 = 16 + c;                      // local gate-row idx
    const uint32_t sw0 = (uint32_t)((j0 & 7) << 4);     // LDS XOR swizzle
    const uint32_t sw1 = (uint32_t)((j1 & 7) << 4);

    for (int p = 0; p < 194; ++p) {
        // ---- wait: all 128 domain-g blocks (64 L0 + 64 L1) finished p-1 ----
        if (p > 0) {
            if (tid < 128) {
                int pid = (tid < 64) ? (g * 64 + tid) : (128 + g * 64 + (tid - 64));
                while (__hip_atomic_load(&stamp[pid * 16], __ATOMIC_RELAXED,
                                         __HIP_MEMORY_SCOPE_AGENT) < (uint32_t)p)
                    __builtin_amdgcn_s_sleep(1);
            }
            __syncthreads();
        }

        if (isL0) {
            const int t = p;
            if (t < 192) {
                // stage x_t (128 batches x 8ch fp32) into LDS
                for (int idx = tid; idx < 1024; idx += 256) {
                    int bl = idx >> 3, ch = idx & 7;
                    int b = g * 128 + bl;
                    ldsF[16384 + idx] = (t < 96)
                        ? x_enc[(b * 96 + t) * 9 + ch]
                        : y_enc[(b * 96 + (t - 96)) * 9 + ch];
                }
                __syncthreads();

                const uint16_t* hbh = hs0hi + ((t + 3) & 3) * SLOT;   // h0(t-1)
                const uint16_t* hbl = hs0lo + ((t + 3) & 3) * SLOT;
                const int ar0 = (g * 128 + w * 32 + c) * 512 + kg * 8;
                const int ar1 = ar0 + 16 * 512;
                const uint32_t bb0 = (uint32_t)(j0 * 1024 + kg * 16);
                const uint32_t bb1 = (uint32_t)(j1 * 1024 + kg * 16);
                f32x4 acc00 = {0.f,0.f,0.f,0.f}, acc01 = acc00, acc10 = acc00, acc11 = acc00;
#pragma unroll
                for (int ks = 0; ks < 16; ++ks) {
                    bf16x8 a0h = ld_h16(hbh + ar0 + ks * 32);
                    bf16x8 a0l = ld_h16(hbl + ar0 + ks * 32);
                    bf16x8 a1h = ld_h16(hbh + ar1 + ks * 32);
                    bf16x8 a1l = ld_h16(hbl + ar1 + ks * 32);
                    uint32_t o0 = (bb0 + ks * 64) ^ sw0;
                    uint32_t o1 = (bb1 + ks * 64) ^ sw1;
                    bf16x8 b0h = *(const bf16x8*)(LDS + o0);
                    bf16x8 b0l = *(const bf16x8*)(LDS + 32768 + o0);
                    bf16x8 b1h = *(const bf16x8*)(LDS + o1);
                    bf16x8 b1l = *(const bf16x8*)(LDS + 32768 + o1);
                    acc00 = __builtin_amdgcn_mfma_f32_16x16x32_bf16(a0h, b0h, acc00, 0, 0, 0);
                    acc00 = __builtin_amdgcn_mfma_f32_16x16x32_bf16(a0h, b0l, acc00, 0, 0, 0);
                    acc00 = __builtin_amdgcn_mfma_f32_16x16x32_bf16(a0l, b0h, acc00, 0, 0, 0);
                    acc00 = __builtin_amdgcn_mfma_f32_16x16x32_bf16(a0l, b0l, acc00, 0, 0, 0);
                    acc01 = __builtin_amdgcn_mfma_f32_16x16x32_bf16(a0h, b1h, acc01, 0, 0, 0);
                    acc01 = __builtin_amdgcn_mfma_f32_16x16x32_bf16(a0h, b1l, acc01, 0, 0, 0);
                    acc01 = __builtin_amdgcn_mfma_f32_16x16x32_bf16(a0l, b1h, acc01, 0, 0, 0);
                    acc01 = __builtin_amdgcn_mfma_f32_16x16x32_bf16(a0l, b1l, acc01, 0, 0, 0);
                    acc10 = __builtin_amdgcn_mfma_f32_16x16x32_bf16(a1h, b0h, acc10, 0, 0, 0);
                    acc10 = __builtin_amdgcn_mfma_f32_16x16x32_bf16(a1h, b0l, acc10, 0, 0, 0);
                    acc10 = __builtin_amdgcn_mfma_f32_16x16x32_bf16(a1l, b0h, acc10, 0, 0, 0);
                    acc10 = __builtin_amdgcn_mfma_f32_16x16x32_bf16(a1l, b0l, acc10, 0, 0, 0);
                    acc11 = __builtin_amdgcn_mfma_f32_16x16x32_bf16(a1h, b1h, acc11, 0, 0, 0);
                    acc11 = __builtin_amdgcn_mfma_f32_16x16x32_bf16(a1h, b1l, acc11, 0, 0, 0);
                    acc11 = __builtin_amdgcn_mfma_f32_16x16x32_bf16(a1l, b1h, acc11, 0, 0, 0);
                    acc11 = __builtin_amdgcn_mfma_f32_16x16x32_bf16(a1l, b1l, acc11, 0, 0, 0);
                }
                // gate recombine across lane pairs (l, l^8), then cell update
                float rv0[4], rv1[4];
#pragma unroll
                for (int r = 0; r < 4; ++r) {
                    rv0[r] = __shfl_xor(lowc ? acc10[r] : acc00[r], 8);
                    rv1[r] = __shfl_xor(lowc ? acc11[r] : acc01[r], 8);
                }
                uint32_t* d32h = (uint32_t*)(hs0hi + (t & 3) * SLOT);
                uint32_t* d32l = (uint32_t*)(hs0lo + (t & 3) * SLOT);
#pragma unroll
                for (int r = 0; r < 4; ++r) {
                    float k0 = lowc ? acc00[r] : acc10[r];
                    float k1 = lowc ? acc01[r] : acc11[r];
                    float gi = lowc ? k0 : rv0[r];
                    float gf = lowc ? rv0[r] : k0;
                    float gG = lowc ? k1 : rv1[r];
                    float go = lowc ? rv1[r] : k1;
                    int m  = (lowc ? 0 : 16) + kg * 4 + r;
                    int bl = w * 32 + m;
                    const float* xr = ldsF + 16384 + bl * 8;
                    const float* wi = ldsF + 17408;
                    float xp0 = 0, xp1 = 0, xp2 = 0, xp3 = 0;
#pragma unroll
                    for (int k = 0; k < 8; ++k) {
                        float xv = xr[k];
                        xp0 += xv * wi[(h) * 8 + k];
                        xp1 += xv * wi[(8 + h) * 8 + k];
                        xp2 += xv * wi[(16 + h) * 8 + k];
                        xp3 += xv * wi[(24 + h) * 8 + k];
                    }
                    gi += xp0 + bias[0];
                    gf += xp1 + bias[1];
                    gG += xp2 + bias[2];
                    go += xp3 + bias[3];
                    float cn = sigm(gf) * creg[r] + sigm(gi) * tanhf(gG);
                    float hn = sigm(go) * tanhf(cn);
                    creg[r] = cn;
                    uint16_t hh = f2bf(hn);
                    uint16_t ll = f2bf(hn - bf2f(hh));
                    // pack lane pair (h, h^1) into one u32 agent store
                    uint32_t phi = (uint32_t)__shfl_xor((int)(uint32_t)hh, 1);
                    uint32_t plo = (uint32_t)__shfl_xor((int)(uint32_t)ll, 1);
                    int eoff = ((g * 128 + bl) * 512 + s * 8 + (h & ~1)) >> 1;
                    if ((h & 1) == 0)
                        __hip_atomic_store(d32h + eoff, (uint32_t)hh | (phi << 16),
                                           __ATOMIC_RELAXED, __HIP_MEMORY_SCOPE_AGENT);
                    else
                        __hip_atomic_store(d32l + eoff, plo | ((uint32_t)ll << 16),
                                           __ATOMIC_RELAXED, __HIP_MEMORY_SCOPE_AGENT);
                }
            }
            // ---- projection for step t2 = p-2 (2 batches x 9 outs per block) ----
            const int t2 = p - 2;
            if (t2 >= 0) {
                float* ps = ldsF + 17664;
                if (tid < 144) {
                    int bi = tid / 72;
                    int rem = tid % 72;
                    int co = rem >> 3, seg = rem & 7;
                    int b = g * 128 + s * 2 + bi;
                    const uint64_t* p0h = (const uint64_t*)(hs0hi + (t2 & 3) * SLOT + b * 512);
                    const uint64_t* p0l = (const uint64_t*)(hs0lo + (t2 & 3) * SLOT + b * 512);
                    const uint64_t* p1h = (const uint64_t*)(hs1hi + (t2 & 3) * SLOT + b * 512);
                    const uint64_t* p1l = (const uint64_t*)(hs1lo + (t2 & 3) * SLOT + b * 512);
                    const float* wr = Wout + co * 1024;
                    float sum = 0.f;
#pragma unroll 4
                    for (int q = seg * 16; q < seg * 16 + 16; ++q) {
                        uint64_t u0 = ld_h64(p0h + q);
                        uint64_t u1 = ld_h64(p0l + q);
                        uint64_t u2 = ld_h64(p1h + q);
                        uint64_t u3 = ld_h64(p1l + q);
#pragma unroll
                        for (int e = 0; e < 4; ++e) {
                            int hh_ = q * 4 + e;
                            float h0v = bf2f((uint16_t)(u0 >> (16 * e))) + bf2f((uint16_t)(u1 >> (16 * e)));
                            float h1v = bf2f((uint16_t)(u2 >> (16 * e))) + bf2f((uint16_t)(u3 >> (16 * e)));
                            sum += h0v * wr[2 * hh_] + h1v * wr[2 * hh_ + 1];
                        }
                    }
                    ps[tid] = sum;
                }
                __syncthreads();
                if (tid < 18) {
                    int bi = tid / 9, co = tid % 9;
                    float tot = bout[co];
#pragma unroll
                    for (int k2 = 0; k2 < 8; ++k2) tot += ps[bi * 72 + co * 8 + k2];
                    out[((g * 128 + s * 2 + bi) * 192 + t2) * 9 + co] = tot;
                }
            }
        } else {
            const int t = p - 1;
            if (t >= 0 && t < 192) {
                const uint16_t* hbah = hs0hi + (t & 3) * SLOT;        // h0(t)
                const uint16_t* hbal = hs0lo + (t & 3) * SLOT;
                const uint16_t* hbbh = hs1hi + ((t + 3) & 3) * SLOT;  // h1(t-1)
                const uint16_t* hbbl = hs1lo + ((t + 3) & 3) * SLOT;
                const int ar0 = (g * 128 + w * 32 + c) * 512 + kg * 8;
                const int ar1 = ar0 + 16 * 512;
                const uint32_t bb0 = (uint32_t)(j0 * 2048 + kg * 16);
                const uint32_t bb1 = (uint32_t)(j1 * 2048 + kg * 16);
                f32x4 acc00 = {0.f,0.f,0.f,0.f}, acc01 = acc00, acc10 = acc00, acc11 = acc00;
#pragma unroll
                for (int ks = 0; ks < 32; ++ks) {
                    const uint16_t* hbh = (ks < 16) ? hbah : hbbh;
                    const uint16_t* hbl = (ks < 16) ? hbal : hbbl;
                    int ko = (ks & 15) * 32;
                    bf16x8 a0h = ld_h16(hbh + ar0 + ko);
                    bf16x8 a0l = ld_h16(hbl + ar0 + ko);
                    bf16x8 a1h = ld_h16(hbh + ar1 + ko);
                    bf16x8 a1l = ld_h16(hbl + ar1 + ko);
                    uint32_t o0 = (bb0 + ks * 64) ^ sw0;
                    uint32_t o1 = (bb1 + ks * 64) ^ sw1;
                    bf16x8 b0h = *(const bf16x8*)(LDS + o0);
                    bf16x8 b0l = *(const bf16x8*)(LDS + 65536 + o0);
                    bf16x8 b1h = *(const bf16x8*)(LDS + o1);
                    bf16x8 b1l = *(const bf16x8*)(LDS + 65536 + o1);
                    acc00 = __builtin_amdgcn_mfma_f32_16x16x32_bf16(a0h, b0h, acc00, 0, 0, 0);
                    acc00 = __builtin_amdgcn_mfma_f32_16x16x32_bf16(a0h, b0l, acc00, 0, 0, 0);
                    acc00 = __builtin_amdgcn_mfma_f32_16x16x32_bf16(a0l, b0h, acc00, 0, 0, 0);
                    acc00 = __builtin_amdgcn_mfma_f32_16x16x32_bf16(a0l, b0l, acc00, 0, 0, 0);
                    acc01 = __builtin_amdgcn_mfma_f32_16x16x32_bf16(a0h, b1h, acc01, 0, 0, 0);
                    acc01 = __builtin_amdgcn_mfma_f32_16x16x32_bf16(a0h, b1l, acc01, 0, 0, 0);
                    acc01 = __builtin_amdgcn_mfma_f32_16x16x32_bf16(a0l, b1h, acc01, 0, 0, 0);
                    acc01 = __builtin_amdgcn_mfma_f32_16x16x32_bf16(a0l, b1l, acc01, 0, 0, 0);
                    acc10 = __builtin_amdgcn_mfma_f32_16x16x32_bf16(a1h, b0h, acc10, 0, 0, 0);
                    acc10 = __builtin_amdgcn_mfma_f32_16x16x32_bf16(a1h, b0l, acc10, 0, 0, 0);
                    acc10 = __builtin_amdgcn_mfma_f32_16x16x32_bf16(a1l, b0h, acc10, 0, 0, 0);
                    acc10 = __builtin_amdgcn_mfma_f32_16x16x32_bf16(a1l, b0l, acc10, 0, 0, 0);
                    acc11 = __builtin_amdgcn_mfma_f32_16x16x32_bf16(a1h, b1h, acc11, 0, 0, 0);
                    acc11 = __builtin_amdgcn_mfma_f32_16x16x32_bf16(a1h, b1l, acc11, 0, 0, 0);
                    acc11 = __builtin_amdgcn_mfma_f32_16x16x32_bf16(a1l, b1h, acc11, 0, 0, 0);
                    acc11 = __builtin_amdgcn_mfma_f32_16x16x32_bf16(a1l, b1l, acc11, 0, 0, 0);
                }
                float rv0[4], rv1[4];
#pragma unroll
                for (int r = 0; r < 4; ++r) {
                    rv0[r] = __shfl_xor(lowc ? acc10[r] : acc00[r], 8);
                    rv1[r] = __shfl_xor(lowc ? acc11[r] : acc01[r], 8);
                }
                uint32_t* d32h = (uint32_t*)(hs1hi + (t & 3) * SLOT);
                uint32_t* d32l = (uint32_t*)(hs1lo + (t & 3) * SLOT);
#pragma unroll
                for (int r = 0; r < 4; ++r) {
                    float k0 = lowc ? acc00[r] : acc10[r];
                    float k1 = lowc ? acc01[r] : acc11[r];
                    float gi = (lowc ? k0 : rv0[r]) + bias[0];
                    float gf = (lowc ? rv0[r] : k0) + bias[1];
                    float gG = (lowc ? k1 : rv1[r]) + bias[2];
                    float go = (lowc ? rv1[r] : k1) + bias[3];
                    int m  = (lowc ? 0 : 16) + kg * 4 + r;
                    int bl = w * 32 + m;
                    float cn = sigm(gf) * creg[r] + sigm(gi) * tanhf(gG);
                    float hn = sigm(go) * tanhf(cn);
                    creg[r] = cn;
                    uint16_t hh = f2bf(hn);
                    uint16_t ll = f2bf(hn - bf2f(hh));
                    uint32_t phi = (uint32_t)__shfl_xor((int)(uint32_t)hh, 1);
                    uint32_t plo = (uint32_t)__shfl_xor((int)(uint32_t)ll, 1);
                    int eoff = ((g * 128 + bl) * 512 + s * 8 + (h & ~1)) >> 1;
                    if ((h & 1) == 0)
                        __hip_atomic_store(d32h + eoff, (uint32_t)hh | (phi << 16),
                                           __ATOMIC_RELAXED, __HIP_MEMORY_SCOPE_AGENT);
                    else
                        __hip_atomic_store(d32l + eoff, plo | ((uint32_t)ll << 16),
                                           __ATOMIC_RELAXED, __HIP_MEMORY_SCOPE_AGENT);
                }
            }
        }

        // ---- publish: drain own stores (sc1 -> coherence point), then stamp ----
        asm volatile("s_waitcnt vmcnt(0)" ::: "memory");
        __syncthreads();
        if (tid == 0)
            __hip_atomic_store(&stamp[bid * 16], (uint32_t)(p + 1),
                               __ATOMIC_RELAXED, __HIP_MEMORY_SCOPE_AGENT);
    }
}

// second tuple output: batch = concat(x_enc, y_enc) -> out[442368..884735]
__global__ void __launch_bounds__(256)
copy_batch(const float* __restrict__ x_enc, const float* __restrict__ y_enc,
           float* __restrict__ out)
{
    int idx = blockIdx.x * 256 + threadIdx.x;
    if (idx >= 256 * 192 * 9) return;
    int b = idx / 1728;
    int rem = idx % 1728;
    int t = rem / 9, ch = rem % 9;
    float v = (t < 96) ? x_enc[b * 864 + t * 9 + ch]
                       : y_enc[b * 864 + (t - 96) * 9 + ch];
    out[442368 + idx] = v;
}

extern "C" void kernel_launch(void* const* d_in, const int* in_sizes, int n_in,
                              void* d_out, int out_size, void* d_ws, size_t ws_size,
                              hipStream_t stream) {
    const float* x_enc = (const float*)d_in[0];
    const float* y_enc = (const float*)d_in[3];
    const float* Wih0  = (const float*)d_in[5];
    const float* Whh0  = (const float*)d_in[6];
    const float* bih0  = (const float*)d_in[7];
    const float* bhh0  = (const float*)d_in[8];
    const float* Wih1  = (const float*)d_in[9];
    const float* Whh1  = (const float*)d_in[10];
    const float* bih1  = (const float*)d_in[11];
    const float* bhh1  = (const float*)d_in[12];
    const float* Wout  = (const float*)d_in[13];
    const float* bout  = (const float*)d_in[14];
    float* out = (float*)d_out;
    uint32_t* stamp = (uint32_t*)d_ws;            // [0,16K): per-block stamps (64B stride)
    uint16_t* hs0hi = (uint16_t*)((uint8_t*)d_ws + 16384);
    uint16_t* hs0lo = hs0hi + 4 * SLOT;
    uint16_t* hs1hi = hs0lo + 4 * SLOT;
    uint16_t* hs1lo = hs1hi + 4 * SLOT;           // rings: 4 MB total

    hipLaunchKernelGGL(copy_batch, dim3(1728), dim3(256), 0, stream,
                       x_enc, y_enc, out);

    hipFuncSetAttribute((const void*)lstm_kernel,
                        hipFuncAttributeMaxDynamicSharedMemorySize, 131072);

    void* args[] = { (void*)&x_enc, (void*)&y_enc, (void*)&Wih0, (void*)&Whh0,
                     (void*)&bih0, (void*)&bhh0, (void*)&Wih1, (void*)&Whh1,
                     (void*)&bih1, (void*)&bhh1, (void*)&Wout, (void*)&bout,
                     (void*)&out, (void*)&stamp, (void*)&hs0hi, (void*)&hs0lo,
                     (void*)&hs1hi, (void*)&hs1lo };
    hipLaunchCooperativeKernel((const void*)lstm_kernel, dim3(256), dim3(256),
                               args, 131072, stream);
}

// Round 14
// 6158.455 us; speedup vs baseline: 1.0065x; 1.0065x over previous
//
#include <hip/hip_runtime.h>
#include <hip/hip_cooperative_groups.h>
#include <cstdint>

namespace cg = cooperative_groups;

// B=256, H=512, T=192 timesteps, 4H=2048 gate rows.
// Grid: 256 blocks x 512 threads (8 waves, 2/SIMD), 1 block/CU (128KB LDS).
//   blocks [0,128):   layer-0. group g = bid>>6, slice s = bid&63
//   blocks [128,256): layer-1. same (g,s) decomposition.
// Slice s owns gate rows n = s*8 + (j&7) + 512*(j>>3), j=0..31.
// Phases p=0..193: L0 computes t=p, L1 computes t=p-1, projection emits t=p-2.
// Precision: h and recurrent W kept as bf16 hi+lo pairs; 4 cross-product MFMAs.
// Sync: stamp barrier (R10). THIS ROUND: TLP. Each wave owns 16 batches
// (w*16..w*16+15) -> ONE A-fragment pair per K-iter (a0h/a0l), acc00/acc01
// (cols 0..31). Per-wave loads halved, 2 waves/SIMD cover vmcnt stalls.
// Gate recombine via shfl_xor(8) as before; lane pairs (c, c^8) hold duplicate
// gate sets -> lowc lanes update r={0,1}, highc r={2,3} (creg[2]).
// d_ws: [0,16K) stamps (256 x 16 u32); rings hs{0,1}{hi,lo} [4][256][512] bf16.

typedef __bf16 bf16x8 __attribute__((ext_vector_type(8)));
typedef float f32x4 __attribute__((ext_vector_type(4)));

#define SLOT 131072  // 256*512 elements per ring slot

__device__ __forceinline__ uint16_t f2bf(float f) {
    uint32_t u = __builtin_bit_cast(uint32_t, f);
    u += 0x7FFFu + ((u >> 16) & 1u);          // round-to-nearest-even
    return (uint16_t)(u >> 16);
}
__device__ __forceinline__ float bf2f(uint16_t h) {
    return __builtin_bit_cast(float, (uint32_t)h << 16);
}
__device__ __forceinline__ float sigm(float x) { return 1.0f / (1.0f + expf(-x)); }

// agent-scope (cross-XCD coherent, sc1) 16-byte h-fragment load as 2 x u64
__device__ __forceinline__ bf16x8 ld_h16(const uint16_t* p) {
    const uint64_t* q = (const uint64_t*)p;
    uint64_t w0 = __hip_atomic_load(q,     __ATOMIC_RELAXED, __HIP_MEMORY_SCOPE_AGENT);
    uint64_t w1 = __hip_atomic_load(q + 1, __ATOMIC_RELAXED, __HIP_MEMORY_SCOPE_AGENT);
    union { uint64_t u[2]; bf16x8 v; } x;
    x.u[0] = w0; x.u[1] = w1;
    return x.v;
}
__device__ __forceinline__ uint64_t ld_h64(const uint64_t* q) {
    return __hip_atomic_load(q, __ATOMIC_RELAXED, __HIP_MEMORY_SCOPE_AGENT);
}

__global__ void __launch_bounds__(512, 2)
lstm_kernel(const float* __restrict__ x_enc, const float* __restrict__ y_enc,
            const float* __restrict__ Wih0, const float* __restrict__ Whh0,
            const float* __restrict__ bih0, const float* __restrict__ bhh0,
            const float* __restrict__ Wih1, const float* __restrict__ Whh1,
            const float* __restrict__ bih1, const float* __restrict__ bhh1,
            const float* __restrict__ Wout, const float* __restrict__ bout,
            float* __restrict__ out,
            uint32_t* __restrict__ stamp,
            uint16_t* __restrict__ hs0hi, uint16_t* __restrict__ hs0lo,
            uint16_t* __restrict__ hs1hi, uint16_t* __restrict__ hs1lo)
{
    extern __shared__ __align__(16) uint8_t LDS[];
    float* ldsF = (float*)LDS;

    const int tid = threadIdx.x;
    const int bid = blockIdx.x;
    const bool isL0 = (bid < 128);
    const int rb = isL0 ? bid : (bid - 128);
    const int g = rb >> 6;
    const int s = rb & 63;

    const int w  = tid >> 6;   // wave 0..7 -> batch rows w*16..w*16+15 of group
    const int l  = tid & 63;
    const int c  = l & 15;
    const int kg = l >> 4;
    const int h  = c & 7;      // h-index within slice handled by this lane
    const bool lowc = (c < 8);

    // ---------------- one-time init ----------------
    if (isL0) {
        for (int idx = tid; idx < 32 * 512; idx += 512) {
            int j = idx >> 9, k = idx & 511;
            int n = s * 8 + (j & 7) + 512 * (j >> 3);
            float v = Whh0[n * 512 + k];
            uint16_t hi = f2bf(v);
            uint16_t lo = f2bf(v - bf2f(hi));
            uint32_t byte = (uint32_t)(j * 1024 + k * 2) ^ (uint32_t)((j & 7) << 4);
            *(uint16_t*)(LDS + byte) = hi;
            *(uint16_t*)(LDS + 32768 + byte) = lo;
        }
        if (tid < 256) {   // Wih0 slice (32 rows x 8) fp32
            int j = tid >> 3, k = tid & 7;
            int n = s * 8 + (j & 7) + 512 * (j >> 3);
            ldsF[17408 + tid] = Wih0[n * 8 + k];
        }
    } else {
        for (int idx = tid; idx < 32 * 1024; idx += 512) {
            int j = idx >> 10, k = idx & 1023;
            int n = s * 8 + (j & 7) + 512 * (j >> 3);
            float v = (k < 512) ? Wih1[n * 512 + k] : Whh1[n * 512 + (k - 512)];
            uint16_t hi = f2bf(v);
            uint16_t lo = f2bf(v - bf2f(hi));
            uint32_t byte = (uint32_t)(j * 2048 + k * 2) ^ (uint32_t)((j & 7) << 4);
            *(uint16_t*)(LDS + byte) = hi;
            *(uint16_t*)(LDS + 65536 + byte) = lo;
        }
    }
    float bias[4];
#pragma unroll
    for (int gt = 0; gt < 4; ++gt) {
        int n = s * 8 + h + 512 * gt;
        bias[gt] = isL0 ? (bih0[n] + bhh0[n]) : (bih1[n] + bhh1[n]);
    }
    if (tid < 256) {  // zero ring slot 3 (t=-1 state); 65536 u32 words per buffer
        int idx = bid * 256 + tid;
        __hip_atomic_store(((uint32_t*)(hs0hi + 3 * SLOT)) + idx, 0u, __ATOMIC_RELAXED, __HIP_MEMORY_SCOPE_AGENT);
        __hip_atomic_store(((uint32_t*)(hs0lo + 3 * SLOT)) + idx, 0u, __ATOMIC_RELAXED, __HIP_MEMORY_SCOPE_AGENT);
        __hip_atomic_store(((uint32_t*)(hs1hi + 3 * SLOT)) + idx, 0u, __ATOMIC_RELAXED, __HIP_MEMORY_SCOPE_AGENT);
        __hip_atomic_store(((uint32_t*)(hs1lo + 3 * SLOT)) + idx, 0u, __ATOMIC_RELAXED, __HIP_MEMORY_SCOPE_AGENT);
    }
    if (tid == 0)   // re-zero own stamp (d_ws is poisoned before every launch)
        __hip_atomic_store(&stamp[bid * 16], 0u, __ATOMIC_RELAXED, __HIP_MEMORY_SCOPE_AGENT);
    float creg[2] = {0.f, 0.f};   // fp32 cell state (2 batch rows / lane)

    cg::grid_group grid = cg::this_grid();
    grid.sync();   // one-time rendezvous: rings/stamps initialized everywhere

    const int j0 = c, j1 = 16 + c;                      // local gate-row idx
    const uint32_t sw0 = (uint32_t)((j0 & 7) << 4);     // LDS XOR swizzle
    const uint32_t sw1 = (uint32_t)((j1 & 7) << 4);

    for (int p = 0; p < 194; ++p) {
        // ---- wait: all 128 domain-g blocks (64 L0 + 64 L1) finished p-1 ----
        if (p > 0) {
            if (tid < 128) {
                int pid = (tid < 64) ? (g * 64 + tid) : (128 + g * 64 + (tid - 64));
                while (__hip_atomic_load(&stamp[pid * 16], __ATOMIC_RELAXED,
                                         __HIP_MEMORY_SCOPE_AGENT) < (uint32_t)p)
                    __builtin_amdgcn_s_sleep(1);
            }
            __syncthreads();
        }

        if (isL0) {
            const int t = p;
            if (t < 192) {
                // stage x_t (128 batches x 8ch fp32) into LDS
                for (int idx = tid; idx < 1024; idx += 512) {
                    int bl = idx >> 3, ch = idx & 7;
                    int b = g * 128 + bl;
                    ldsF[16384 + idx] = (t < 96)
                        ? x_enc[(b * 96 + t) * 9 + ch]
                        : y_enc[(b * 96 + (t - 96)) * 9 + ch];
                }
                __syncthreads();

                const uint16_t* hbh = hs0hi + ((t + 3) & 3) * SLOT;   // h0(t-1)
                const uint16_t* hbl = hs0lo + ((t + 3) & 3) * SLOT;
                const int ar0 = (g * 128 + w * 16 + c) * 512 + kg * 8;
                const uint32_t bb0 = (uint32_t)(j0 * 1024 + kg * 16);
                const uint32_t bb1 = (uint32_t)(j1 * 1024 + kg * 16);
                f32x4 acc00 = {0.f,0.f,0.f,0.f}, acc01 = acc00;
#pragma unroll
                for (int ks = 0; ks < 16; ++ks) {
                    bf16x8 a0h = ld_h16(hbh + ar0 + ks * 32);
                    bf16x8 a0l = ld_h16(hbl + ar0 + ks * 32);
                    uint32_t o0 = (bb0 + ks * 64) ^ sw0;
                    uint32_t o1 = (bb1 + ks * 64) ^ sw1;
                    bf16x8 b0h = *(const bf16x8*)(LDS + o0);
                    bf16x8 b0l = *(const bf16x8*)(LDS + 32768 + o0);
                    bf16x8 b1h = *(const bf16x8*)(LDS + o1);
                    bf16x8 b1l = *(const bf16x8*)(LDS + 32768 + o1);
                    acc00 = __builtin_amdgcn_mfma_f32_16x16x32_bf16(a0h, b0h, acc00, 0, 0, 0);
                    acc00 = __builtin_amdgcn_mfma_f32_16x16x32_bf16(a0h, b0l, acc00, 0, 0, 0);
                    acc00 = __builtin_amdgcn_mfma_f32_16x16x32_bf16(a0l, b0h, acc00, 0, 0, 0);
                    acc00 = __builtin_amdgcn_mfma_f32_16x16x32_bf16(a0l, b0l, acc00, 0, 0, 0);
                    acc01 = __builtin_amdgcn_mfma_f32_16x16x32_bf16(a0h, b1h, acc01, 0, 0, 0);
                    acc01 = __builtin_amdgcn_mfma_f32_16x16x32_bf16(a0h, b1l, acc01, 0, 0, 0);
                    acc01 = __builtin_amdgcn_mfma_f32_16x16x32_bf16(a0l, b1h, acc01, 0, 0, 0);
                    acc01 = __builtin_amdgcn_mfma_f32_16x16x32_bf16(a0l, b1l, acc01, 0, 0, 0);
                }
                // gate recombine across lane pairs (c, c^8), then cell update
                float rv0[4], rv1[4];
#pragma unroll
                for (int r = 0; r < 4; ++r) {
                    rv0[r] = __shfl_xor(acc00[r], 8);
                    rv1[r] = __shfl_xor(acc01[r], 8);
                }
                uint32_t* d32h = (uint32_t*)(hs0hi + (t & 3) * SLOT);
                uint32_t* d32l = (uint32_t*)(hs0lo + (t & 3) * SLOT);
#pragma unroll
                for (int rr = 0; rr < 2; ++rr) {
                    const float k0   = lowc ? acc00[rr] : acc00[rr + 2];
                    const float k1   = lowc ? acc01[rr] : acc01[rr + 2];
                    const float rv0v = lowc ? rv0[rr]   : rv0[rr + 2];
                    const float rv1v = lowc ? rv1[rr]   : rv1[rr + 2];
                    float gi = lowc ? k0 : rv0v;
                    float gf = lowc ? rv0v : k0;
                    float gG = lowc ? k1 : rv1v;
                    float go = lowc ? rv1v : k1;
                    const int r = (lowc ? 0 : 2) + rr;
                    int bl = w * 16 + kg * 4 + r;
                    const float* xr = ldsF + 16384 + bl * 8;
                    const float* wi = ldsF + 17408;
                    float xp0 = 0, xp1 = 0, xp2 = 0, xp3 = 0;
#pragma unroll
                    for (int k = 0; k < 8; ++k) {
                        float xv = xr[k];
                        xp0 += xv * wi[(h) * 8 + k];
                        xp1 += xv * wi[(8 + h) * 8 + k];
                        xp2 += xv * wi[(16 + h) * 8 + k];
                        xp3 += xv * wi[(24 + h) * 8 + k];
                    }
                    gi += xp0 + bias[0];
                    gf += xp1 + bias[1];
                    gG += xp2 + bias[2];
                    go += xp3 + bias[3];
                    float cn = sigm(gf) * creg[rr] + sigm(gi) * tanhf(gG);
                    float hn = sigm(go) * tanhf(cn);
                    creg[rr] = cn;
                    uint16_t hh = f2bf(hn);
                    uint16_t ll = f2bf(hn - bf2f(hh));
                    // pack lane pair (h, h^1) into one u32 agent store
                    uint32_t phi = (uint32_t)__shfl_xor((int)(uint32_t)hh, 1);
                    uint32_t plo = (uint32_t)__shfl_xor((int)(uint32_t)ll, 1);
                    int eoff = ((g * 128 + bl) * 512 + s * 8 + (h & ~1)) >> 1;
                    if ((h & 1) == 0)
                        __hip_atomic_store(d32h + eoff, (uint32_t)hh | (phi << 16),
                                           __ATOMIC_RELAXED, __HIP_MEMORY_SCOPE_AGENT);
                    else
                        __hip_atomic_store(d32l + eoff, plo | ((uint32_t)ll << 16),
                                           __ATOMIC_RELAXED, __HIP_MEMORY_SCOPE_AGENT);
                }
            }
            // ---- projection for step t2 = p-2 (2 batches x 9 outs per block) ----
            const int t2 = p - 2;
            if (t2 >= 0) {
                float* ps = ldsF + 17664;
                if (tid < 144) {
                    int bi = tid / 72;
                    int rem = tid % 72;
                    int co = rem >> 3, seg = rem & 7;
                    int b = g * 128 + s * 2 + bi;
                    const uint64_t* p0h = (const uint64_t*)(hs0hi + (t2 & 3) * SLOT + b * 512);
                    const uint64_t* p0l = (const uint64_t*)(hs0lo + (t2 & 3) * SLOT + b * 512);
                    const uint64_t* p1h = (const uint64_t*)(hs1hi + (t2 & 3) * SLOT + b * 512);
                    const uint64_t* p1l = (const uint64_t*)(hs1lo + (t2 & 3) * SLOT + b * 512);
                    const float* wr = Wout + co * 1024;
                    float sum = 0.f;
#pragma unroll 4
                    for (int q = seg * 16; q < seg * 16 + 16; ++q) {
                        uint64_t u0 = ld_h64(p0h + q);
                        uint64_t u1 = ld_h64(p0l + q);
                        uint64_t u2 = ld_h64(p1h + q);
                        uint64_t u3 = ld_h64(p1l + q);
#pragma unroll
                        for (int e = 0; e < 4; ++e) {
                            int hh_ = q * 4 + e;
                            float h0v = bf2f((uint16_t)(u0 >> (16 * e))) + bf2f((uint16_t)(u1 >> (16 * e)));
                            float h1v = bf2f((uint16_t)(u2 >> (16 * e))) + bf2f((uint16_t)(u3 >> (16 * e)));
                            sum += h0v * wr[2 * hh_] + h1v * wr[2 * hh_ + 1];
                        }
                    }
                    ps[tid] = sum;
                }
                __syncthreads();
                if (tid < 18) {
                    int bi = tid / 9, co = tid % 9;
                    float tot = bout[co];
#pragma unroll
                    for (int k2 = 0; k2 < 8; ++k2) tot += ps[bi * 72 + co * 8 + k2];
                    out[((g * 128 + s * 2 + bi) * 192 + t2) * 9 + co] = tot;
                }
            }
        } else {
            const int t = p - 1;
            if (t >= 0 && t < 192) {
                const uint16_t* hbah = hs0hi + (t & 3) * SLOT;        // h0(t)
                const uint16_t* hbal = hs0lo + (t & 3) * SLOT;
                const uint16_t* hbbh = hs1hi + ((t + 3) & 3) * SLOT;  // h1(t-1)
                const uint16_t* hbbl = hs1lo + ((t + 3) & 3) * SLOT;
                const int ar0 = (g * 128 + w * 16 + c) * 512 + kg * 8;
                const uint32_t bb0 = (uint32_t)(j0 * 2048 + kg * 16);
                const uint32_t bb1 = (uint32_t)(j1 * 2048 + kg * 16);
                f32x4 acc00 = {0.f,0.f,0.f,0.f}, acc01 = acc00;
#pragma unroll
                for (int ks = 0; ks < 32; ++ks) {
                    const uint16_t* hbh = (ks < 16) ? hbah : hbbh;
                    const uint16_t* hbl = (ks < 16) ? hbal : hbbl;
                    int ko = (ks & 15) * 32;
                    bf16x8 a0h = ld_h16(hbh + ar0 + ko);
                    bf16x8 a0l = ld_h16(hbl + ar0 + ko);
                    uint32_t o0 = (bb0 + ks * 64) ^ sw0;
                    uint32_t o1 = (bb1 + ks * 64) ^ sw1;
                    bf16x8 b0h = *(const bf16x8*)(LDS + o0);
                    bf16x8 b0l = *(const bf16x8*)(LDS + 65536 + o0);
                    bf16x8 b1h = *(const bf16x8*)(LDS + o1);
                    bf16x8 b1l = *(const bf16x8*)(LDS + 65536 + o1);
                    acc00 = __builtin_amdgcn_mfma_f32_16x16x32_bf16(a0h, b0h, acc00, 0, 0, 0);
                    acc00 = __builtin_amdgcn_mfma_f32_16x16x32_bf16(a0h, b0l, acc00, 0, 0, 0);
                    acc00 = __builtin_amdgcn_mfma_f32_16x16x32_bf16(a0l, b0h, acc00, 0, 0, 0);
                    acc00 = __builtin_amdgcn_mfma_f32_16x16x32_bf16(a0l, b0l, acc00, 0, 0, 0);
                    acc01 = __builtin_amdgcn_mfma_f32_16x16x32_bf16(a0h, b1h, acc01, 0, 0, 0);
                    acc01 = __builtin_amdgcn_mfma_f32_16x16x32_bf16(a0h, b1l, acc01, 0, 0, 0);
                    acc01 = __builtin_amdgcn_mfma_f32_16x16x32_bf16(a0l, b1h, acc01, 0, 0, 0);
                    acc01 = __builtin_amdgcn_mfma_f32_16x16x32_bf16(a0l, b1l, acc01, 0, 0, 0);
                }
                float rv0[4], rv1[4];
#pragma unroll
                for (int r = 0; r < 4; ++r) {
                    rv0[r] = __shfl_xor(acc00[r], 8);
                    rv1[r] = __shfl_xor(acc01[r], 8);
                }
                uint32_t* d32h = (uint32_t*)(hs1hi + (t & 3) * SLOT);
                uint32_t* d32l = (uint32_t*)(hs1lo + (t & 3) * SLOT);
#pragma unroll
                for (int rr = 0; rr < 2; ++rr) {
                    const float k0   = lowc ? acc00[rr] : acc00[rr + 2];
                    const float k1   = lowc ? acc01[rr] : acc01[rr + 2];
                    const float rv0v = lowc ? rv0[rr]   : rv0[rr + 2];
                    const float rv1v = lowc ? rv1[rr]   : rv1[rr + 2];
                    float gi = (lowc ? k0 : rv0v) + bias[0];
                    float gf = (lowc ? rv0v : k0) + bias[1];
                    float gG = (lowc ? k1 : rv1v) + bias[2];
                    float go = (lowc ? rv1v : k1) + bias[3];
                    const int r = (lowc ? 0 : 2) + rr;
                    int bl = w * 16 + kg * 4 + r;
                    float cn = sigm(gf) * creg[rr] + sigm(gi) * tanhf(gG);
                    float hn = sigm(go) * tanhf(cn);
                    creg[rr] = cn;
                    uint16_t hh = f2bf(hn);
                    uint16_t ll = f2bf(hn - bf2f(hh));
                    uint32_t phi = (uint32_t)__shfl_xor((int)(uint32_t)hh, 1);
                    uint32_t plo = (uint32_t)__shfl_xor((int)(uint32_t)ll, 1);
                    int eoff = ((g * 128 + bl) * 512 + s * 8 + (h & ~1)) >> 1;
                    if ((h & 1) == 0)
                        __hip_atomic_store(d32h + eoff, (uint32_t)hh | (phi << 16),
                                           __ATOMIC_RELAXED, __HIP_MEMORY_SCOPE_AGENT);
                    else
                        __hip_atomic_store(d32l + eoff, plo | ((uint32_t)ll << 16),
                                           __ATOMIC_RELAXED, __HIP_MEMORY_SCOPE_AGENT);
                }
            }
        }

        // ---- publish: drain own stores (sc1 -> coherence point), then stamp ----
        asm volatile("s_waitcnt vmcnt(0)" ::: "memory");
        __syncthreads();
        if (tid == 0)
            __hip_atomic_store(&stamp[bid * 16], (uint32_t)(p + 1),
                               __ATOMIC_RELAXED, __HIP_MEMORY_SCOPE_AGENT);
    }
}

// second tuple output: batch = concat(x_enc, y_enc) -> out[442368..884735]
__global__ void __launch_bounds__(256)
copy_batch(const float* __restrict__ x_enc, const float* __restrict__ y_enc,
           float* __restrict__ out)
{
    int idx = blockIdx.x * 256 + threadIdx.x;
    if (idx >= 256 * 192 * 9) return;
    int b = idx / 1728;
    int rem = idx % 1728;
    int t = rem / 9, ch = rem % 9;
    float v = (t < 96) ? x_enc[b * 864 + t * 9 + ch]
                       : y_enc[b * 864 + (t - 96) * 9 + ch];
    out[442368 + idx] = v;
}

extern "C" void kernel_launch(void* const* d_in, const int* in_sizes, int n_in,
                              void* d_out, int out_size, void* d_ws, size_t ws_size,
                              hipStream_t stream) {
    const float* x_enc = (const float*)d_in[0];
    const float* y_enc = (const float*)d_in[3];
    const float* Wih0  = (const float*)d_in[5];
    const float* Whh0  = (const float*)d_in[6];
    const float* bih0  = (const float*)d_in[7];
    const float* bhh0  = (const float*)d_in[8];
    const float* Wih1  = (const float*)d_in[9];
    const float* Whh1  = (const float*)d_in[10];
    const float* bih1  = (const float*)d_in[11];
    const float* bhh1  = (const float*)d_in[12];
    const float* Wout  = (const float*)d_in[13];
    const float* bout  = (const float*)d_in[14];
    float* out = (float*)d_out;
    uint32_t* stamp = (uint32_t*)d_ws;            // [0,16K): per-block stamps (64B stride)
    uint16_t* hs0hi = (uint16_t*)((uint8_t*)d_ws + 16384);
    uint16_t* hs0lo = hs0hi + 4 * SLOT;
    uint16_t* hs1hi = hs0lo + 4 * SLOT;
    uint16_t* hs1lo = hs1hi + 4 * SLOT;           // rings: 4 MB total

    hipLaunchKernelGGL(copy_batch, dim3(1728), dim3(256), 0, stream,
                       x_enc, y_enc, out);

    hipFuncSetAttribute((const void*)lstm_kernel,
                        hipFuncAttributeMaxDynamicSharedMemorySize, 131072);

    void* args[] = { (void*)&x_enc, (void*)&y_enc, (void*)&Wih0, (void*)&Whh0,
                     (void*)&bih0, (void*)&bhh0, (void*)&Wih1, (void*)&Whh1,
                     (void*)&bih1, (void*)&bhh1, (void*)&Wout, (void*)&bout,
                     (void*)&out, (void*)&stamp, (void*)&hs0hi, (void*)&hs0lo,
                     (void*)&hs1hi, (void*)&hs1lo };
    hipLaunchCooperativeKernel((const void*)lstm_kernel, dim3(256), dim3(512),
                               args, 131072, stream);
}